// Round 1
// baseline (251.172 us; speedup 1.0000x reference)
//
#include <hip/hip_runtime.h>
#include <hip/hip_bf16.h>

// Sizes
// S=64, C=27
// leaf dot length = C*S*5 = 8640 ; per-node state = S*5 = 320 ; comb = 640 ; hidden = 64

__device__ __forceinline__ float wave_reduce_sum(float v) {
    // full 64-lane butterfly
    v += __shfl_xor(v, 32, 64);
    v += __shfl_xor(v, 16, 64);
    v += __shfl_xor(v, 8, 64);
    v += __shfl_xor(v, 4, 64);
    v += __shfl_xor(v, 2, 64);
    v += __shfl_xor(v, 1, 64);
    return v;
}

// Generic batched GEMV: y[row] = dot(W[row, 0:8640], x[(row/320)*8640 : ...]) + b[row]
// One wave per row. W rows are contiguous 8640 floats (16B aligned: 8640*4 = 34560).
__global__ void __launch_bounds__(256) gemv8640(
    const float* __restrict__ W,   // [rows][8640]
    const float* __restrict__ x,   // [rows/320][8640]
    const float* __restrict__ b,   // [rows]
    float*       __restrict__ y,   // [rows]
    int rows)
{
    int wave = (blockIdx.x * blockDim.x + threadIdx.x) >> 6;
    int lane = threadIdx.x & 63;
    if (wave >= rows) return;
    int node = wave / 320;  // which x-vector this row consumes

    const float4* __restrict__ Wr = reinterpret_cast<const float4*>(W + (size_t)wave * 8640);
    const float4* __restrict__ xr = reinterpret_cast<const float4*>(x + (size_t)node * 8640);

    float acc = 0.f;
    // 8640/4 = 2160 float4 per row; lanes 0..47 do 34 iters, 48..63 do 33.
    for (int j = lane; j < 2160; j += 64) {
        float4 w = Wr[j];
        float4 v = xr[j];
        acc = fmaf(w.x, v.x, acc);
        acc = fmaf(w.y, v.y, acc);
        acc = fmaf(w.z, v.z, acc);
        acc = fmaf(w.w, v.w, acc);
    }
    acc = wave_reduce_sum(acc);
    if (lane == 0) y[wave] = acc + b[wave];
}

// Per level-1 node MLP: comb1 = [states1[n], agg1[n]]; h = relu(W1 @ comb1 + b1);
// new_states1[n] = states1[n] + W2 @ h + b2
__global__ void __launch_bounds__(256) level1_mlp(
    const float* __restrict__ states1,   // [27][320]
    const float* __restrict__ agg1,      // [27][320] (ws)
    const float* __restrict__ W1,        // [27][64][640]
    const float* __restrict__ b1,        // [27][64]
    const float* __restrict__ W2,        // [27][320][64]
    const float* __restrict__ b2,        // [27][320]
    float*       __restrict__ new_states1) // [27][320] (ws)
{
    __shared__ float comb[640];
    __shared__ float h[64];
    const int n   = blockIdx.x;
    const int tid = threadIdx.x;

    for (int j = tid; j < 320; j += 256) {
        comb[j]       = states1[n * 320 + j];
        comb[320 + j] = agg1[n * 320 + j];
    }
    __syncthreads();

    const int wv = tid >> 6, lane = tid & 63;
    const float* __restrict__ W1n = W1 + (size_t)n * 64 * 640;
    // 4 waves x 16 hidden outputs each
    for (int k = wv * 16; k < wv * 16 + 16; ++k) {
        float acc = 0.f;
        #pragma unroll
        for (int j = lane; j < 640; j += 64)
            acc = fmaf(W1n[k * 640 + j], comb[j], acc);
        acc = wave_reduce_sum(acc);
        if (lane == 0) h[k] = fmaxf(acc + b1[n * 64 + k], 0.f);
    }
    __syncthreads();

    const float* __restrict__ W2n = W2 + (size_t)n * 320 * 64;
    for (int i = tid; i < 320; i += 256) {
        float acc = 0.f;
        #pragma unroll
        for (int j = 0; j < 64; ++j)
            acc = fmaf(W2n[i * 64 + j], h[j], acc);
        new_states1[n * 320 + i] = states1[n * 320 + i] + acc + b2[n * 320 + i];
    }
}

// Root: s0 = state0 + ext; comb0 = [s0, agg0]; h = relu(W1 @ comb0 + b1);
// out = s0 + W2 @ h + b2
__global__ void __launch_bounds__(256) root_mlp(
    const float* __restrict__ ext,     // [320]
    const float* __restrict__ state0,  // [320]
    const float* __restrict__ agg0,    // [320] (ws)
    const float* __restrict__ W1,      // [64][640]
    const float* __restrict__ b1,      // [64]
    const float* __restrict__ W2,      // [320][64]
    const float* __restrict__ b2,      // [320]
    float*       __restrict__ out)     // [320]
{
    __shared__ float comb[640];
    __shared__ float h[64];
    const int tid = threadIdx.x;

    for (int i = tid; i < 320; i += 256) {
        float s = state0[i] + ext[i];
        comb[i]       = s;
        comb[320 + i] = agg0[i];
    }
    __syncthreads();

    const int wv = tid >> 6, lane = tid & 63;
    for (int k = wv * 16; k < wv * 16 + 16; ++k) {
        float acc = 0.f;
        #pragma unroll
        for (int j = lane; j < 640; j += 64)
            acc = fmaf(W1[k * 640 + j], comb[j], acc);
        acc = wave_reduce_sum(acc);
        if (lane == 0) h[k] = fmaxf(acc + b1[k], 0.f);
    }
    __syncthreads();

    for (int i = tid; i < 320; i += 256) {
        float acc = 0.f;
        #pragma unroll
        for (int j = 0; j < 64; ++j)
            acc = fmaf(W2[i * 64 + j], h[j], acc);
        out[i] = comb[i] + acc + b2[i];
    }
}

extern "C" void kernel_launch(void* const* d_in, const int* in_sizes, int n_in,
                              void* d_out, int out_size, void* d_ws, size_t ws_size,
                              hipStream_t stream) {
    const float* ext      = (const float*)d_in[0];
    const float* state0   = (const float*)d_in[1];
    const float* states1  = (const float*)d_in[2];
    const float* states2  = (const float*)d_in[3];
    const float* agg_W0   = (const float*)d_in[4];
    const float* agg_b0   = (const float*)d_in[5];
    const float* agg_W1   = (const float*)d_in[6];
    const float* agg_b1   = (const float*)d_in[7];
    const float* up_W1_0  = (const float*)d_in[8];
    const float* up_b1_0  = (const float*)d_in[9];
    const float* up_W2_0  = (const float*)d_in[10];
    const float* up_b2_0  = (const float*)d_in[11];
    const float* up_W1_1  = (const float*)d_in[12];
    const float* up_b1_1  = (const float*)d_in[13];
    const float* up_W2_1  = (const float*)d_in[14];
    const float* up_b2_1  = (const float*)d_in[15];

    float* out  = (float*)d_out;
    float* ws   = (float*)d_ws;
    float* agg1 = ws;            // 8640 floats
    float* ns1  = ws + 8640;     // 8640 floats
    float* agg0 = ws + 17280;    // 320 floats

    // 1) agg1 = agg_W1 . leaf_flat + agg_b1      (27*320 rows, dominant HBM read)
    gemv8640<<<(8640 * 64) / 256 /* =2160 */, 256, 0, stream>>>(agg_W1, states2, agg_b1, agg1, 8640);
    // 2) level-1 update nets -> new_states1
    level1_mlp<<<27, 256, 0, stream>>>(states1, agg1, up_W1_1, up_b1_1, up_W2_1, up_b2_1, ns1);
    // 3) agg0 = agg_W0 . new_states1 + agg_b0   (320 rows)
    gemv8640<<<(320 * 64 + 255) / 256 /* =80 */, 256, 0, stream>>>(agg_W0, ns1, agg_b0, agg0, 320);
    // 4) root update net -> out
    root_mlp<<<1, 256, 0, stream>>>(ext, state0, agg0, up_W1_0, up_b1_0, up_W2_0, up_b2_0, out);
}